// Round 13
// baseline (171.846 us; speedup 1.0000x reference)
//
#include <hip/hip_runtime.h>
#include <hip/hip_bf16.h>
#include <stdint.h>

typedef __attribute__((ext_vector_type(4)))  float  floatx4;
typedef __attribute__((ext_vector_type(8)))  short  short8;
typedef __attribute__((ext_vector_type(8)))  unsigned short ushortx8;
typedef __attribute__((ext_vector_type(4)))  unsigned short ushortx4;

#define B_  2
#define T_  2048
#define E_  1024
#define H_  16
#define D_  64
#define C_  128
#define NC_ 16
#define M_  4096   /* B*T */
#define EPS_ 1e-5f

__device__ __forceinline__ unsigned short f2b(float f) {
    union { float f; unsigned int u; } v; v.f = f;
    unsigned int r = v.u + 0x7fffu + ((v.u >> 16) & 1u);
    return (unsigned short)(r >> 16);
}
__device__ __forceinline__ float b2f(unsigned short b) {
    union { unsigned int u; float f; } v; v.u = ((unsigned int)b) << 16;
    return v.f;
}

// Swizzled fragment staging (R3/R4; R7/R9/R10 errata):
//   staging tile = 16 rows x 32 k (1 KB). lane i fetches global (row = i>>2,
//   kseg = (i&3) ^ ((i>>3)&3)) -> LDS slot i (16B). Fragment read: lane l
//   reads slot sigma(l&15, l>>4) with a WAVE-UNIFORM tile base (R7 errata).
//   R9: fragment operands MUST come from LDS (per-use global = L2-latency serial).
//   R10: do NOT re-swizzle blockIdx. R12: attn j-loop balancing is neutral
//   at 2 blocks/CU (co-resident block absorbs tail-wave idle).
__device__ __forceinline__ int stage_seg(int i) { return (i & 3) ^ ((i >> 3) & 3); }
__device__ __forceinline__ int frag_slot(int lane) {
    int m = lane & 15, q = lane >> 4;
    return m * 4 + (q ^ ((m >> 1) & 3));
}

// ---------------- fused fp32 -> bf16 convert: x | Wq | Wk | Wv | Wo ----------------
__global__ __launch_bounds__(256) void convert_all(const float* __restrict__ x,
                                                   const float* __restrict__ Wq,
                                                   const float* __restrict__ Wk,
                                                   const float* __restrict__ Wv,
                                                   const float* __restrict__ Wo,
                                                   unsigned short* __restrict__ dst) {
    int i = (blockIdx.x * 256 + threadIdx.x) * 4;
    const float* s; int off;
    if (i < M_ * E_) { s = x; off = i; }
    else {
        int j = i - M_ * E_;
        int which = j >> 20;
        s = (which == 0) ? Wq : (which == 1) ? Wk : (which == 2) ? Wv : Wo;
        off = j & ((1 << 20) - 1);
    }
    float4 f = *(const float4*)(s + off);
    ushortx4 o;
    o[0] = f2b(f.x); o[1] = f2b(f.y); o[2] = f2b(f.z); o[3] = f2b(f.w);
    *(ushortx4*)(dst + i) = o;
}

// ---------------- QKV projection GEMM: C[4096,3072] = X @ W^T, phi on q,k ----------------
// R13: 64x64 tile, BK=64, LDS 16 KB (A 8 + B 8), grid 48x64 = 3072 blocks
// = 8 resident/CU = 32 waves/CU (HW max for 256-thr). Follows the R5->R6
// gradient: occupancy dominated a +50% LDS-ratio penalty there; this trades
// +33% LDS reads + 2x A refetch for 24->32 waves/CU.
__global__ __launch_bounds__(256) void gemm_qkv(const unsigned short* __restrict__ A,
                                                const unsigned short* __restrict__ Bm,
                                                unsigned short* __restrict__ Cb) {
    const int N = 3 * E_, K = E_;
    __shared__ __align__(16) unsigned short at[8 * 512];   // 64 rows x 64 k
    __shared__ __align__(16) unsigned short bt[8 * 512];   // 64 cols x 64 k
    int tid = threadIdx.x;
    int wave = tid >> 6, lane = tid & 63;
    int wr = wave >> 1, wc = wave & 1;
    int m = lane & 15, q = lane >> 4;
    int srow = lane >> 2, sseg = stage_seg(lane);
    int fs = frag_slot(lane);
    int row0 = blockIdx.y * 64, col0 = blockIdx.x * 64;
    floatx4 acc[2][2];
    for (int i = 0; i < 2; i++) for (int j = 0; j < 2; j++) acc[i][j] = floatx4{0.f, 0.f, 0.f, 0.f};

    for (int k0 = 0; k0 < K; k0 += 64) {
        __syncthreads();
        for (int p = 0; p < 2; p++) {
            int t = p * 4 + wave;                   // 0..7: rt = t&3, kh = t>>2
            const unsigned short* ga = A  + (size_t)(row0 + (t & 3) * 16 + srow) * K + k0 + (t >> 2) * 32 + sseg * 8;
            const unsigned short* gb = Bm + (size_t)(col0 + (t & 3) * 16 + srow) * K + k0 + (t >> 2) * 32 + sseg * 8;
            __builtin_amdgcn_global_load_lds((const __attribute__((address_space(1))) unsigned int*)ga,
                (__attribute__((address_space(3))) unsigned int*)(at + t * 512), 16, 0, 0);
            __builtin_amdgcn_global_load_lds((const __attribute__((address_space(1))) unsigned int*)gb,
                (__attribute__((address_space(3))) unsigned int*)(bt + t * 512), 16, 0, 0);
        }
        __syncthreads();
        for (int kh = 0; kh < 2; kh++) {
            short8 af[2], bf[2];
            for (int mi = 0; mi < 2; mi++) af[mi] = *(const short8*)(at + (kh * 4 + wr * 2 + mi) * 512 + fs * 8);
            for (int ci = 0; ci < 2; ci++) bf[ci] = *(const short8*)(bt + (kh * 4 + wc * 2 + ci) * 512 + fs * 8);
            for (int mi = 0; mi < 2; mi++)
                for (int ci = 0; ci < 2; ci++)
                    acc[mi][ci] = __builtin_amdgcn_mfma_f32_16x16x32_bf16(af[mi], bf[ci], acc[mi][ci], 0, 0, 0);
        }
    }
    int qrow = q * 4;
    for (int mi = 0; mi < 2; mi++) for (int ci = 0; ci < 2; ci++) {
        int col = col0 + wc * 32 + ci * 16 + m;
        bool isphi = (col < 2 * E_);
        for (int r2 = 0; r2 < 4; r2++) {
            int row = row0 + wr * 32 + mi * 16 + qrow + r2;
            float v = acc[mi][ci][r2];
            if (isphi) v = (v > 0.f) ? (v + 1.f) : __expf(v);
            Cb[(size_t)row * N + col] = f2b(v);
        }
    }
}

// ---------------- Output GEMM: out[4096,1024] = attn @ Wo^T + bo (fp32 out) ----------------
// Exact R6 config: 64x64 tile, BK=64, grid 16x64 = 1024 = 4/CU, LDS 16 KB.
__global__ __launch_bounds__(256) void gemm_out(const unsigned short* __restrict__ A,
                                                const unsigned short* __restrict__ Bm,
                                                const float* __restrict__ bias,
                                                float* __restrict__ Cf) {
    const int N = E_, K = E_;
    __shared__ __align__(16) unsigned short at[8 * 512];
    __shared__ __align__(16) unsigned short bt[8 * 512];
    int tid = threadIdx.x;
    int wave = tid >> 6, lane = tid & 63;
    int wr = wave >> 1, wc = wave & 1;
    int m = lane & 15, q = lane >> 4;
    int srow = lane >> 2, sseg = stage_seg(lane);
    int fs = frag_slot(lane);
    int row0 = blockIdx.y * 64, col0 = blockIdx.x * 64;
    floatx4 acc[2][2];
    for (int i = 0; i < 2; i++) for (int j = 0; j < 2; j++) acc[i][j] = floatx4{0.f, 0.f, 0.f, 0.f};

    for (int k0 = 0; k0 < K; k0 += 64) {
        __syncthreads();
        for (int p = 0; p < 2; p++) {
            int t = p * 4 + wave;
            int rt = t & 3, kh = t >> 2;
            const unsigned short* ga = A  + (size_t)(row0 + rt * 16 + srow) * K + k0 + kh * 32 + sseg * 8;
            const unsigned short* gb = Bm + (size_t)(col0 + rt * 16 + srow) * K + k0 + kh * 32 + sseg * 8;
            __builtin_amdgcn_global_load_lds((const __attribute__((address_space(1))) unsigned int*)ga,
                (__attribute__((address_space(3))) unsigned int*)(at + t * 512), 16, 0, 0);
            __builtin_amdgcn_global_load_lds((const __attribute__((address_space(1))) unsigned int*)gb,
                (__attribute__((address_space(3))) unsigned int*)(bt + t * 512), 16, 0, 0);
        }
        __syncthreads();
        for (int kh = 0; kh < 2; kh++) {
            short8 af[2], bf[2];
            for (int mi = 0; mi < 2; mi++) af[mi] = *(const short8*)(at + (kh * 4 + wr * 2 + mi) * 512 + fs * 8);
            for (int ci = 0; ci < 2; ci++) bf[ci] = *(const short8*)(bt + (kh * 4 + wc * 2 + ci) * 512 + fs * 8);
            for (int mi = 0; mi < 2; mi++)
                for (int ci = 0; ci < 2; ci++)
                    acc[mi][ci] = __builtin_amdgcn_mfma_f32_16x16x32_bf16(af[mi], bf[ci], acc[mi][ci], 0, 0, 0);
        }
    }
    int qrow = q * 4;
    for (int ci = 0; ci < 2; ci++) {
        int col = col0 + wc * 32 + ci * 16 + m;
        float bv = bias[col];
        for (int mi = 0; mi < 2; mi++)
            for (int r2 = 0; r2 < 4; r2++) {
                int row = row0 + wr * 32 + mi * 16 + qrow + r2;
                Cf[(size_t)row * N + col] = acc[mi][ci][r2] + bv;
            }
    }
}

// ---------------- per-chunk S_c = k_c^T v_c (64x64) and z_c (MFMA) ----------------
__global__ __launch_bounds__(256) void chunk_sums(const unsigned short* __restrict__ qkv,
                                                  float* __restrict__ Sc, float* __restrict__ zc) {
    int c = blockIdx.x, h = blockIdx.y, bb = blockIdx.z;
    __shared__ __align__(16) unsigned short Kt[64 * 132];   // K^T: [d][t], stride 132
    __shared__ __align__(16) unsigned short Vt[80 * 132];   // V^T rows 0..63; row 64 = ones
    int tid = threadIdx.x;
    int lane = tid & 63, w = tid >> 6;
    size_t rowb = (size_t)bb * T_ + (size_t)c * C_;
    int kcol = E_ + h * D_, vcol = 2 * E_ + h * D_;

    {
        int r4 = (tid >> 3) * 4;            // covers 128 rows
        int seg = (tid & 7) * 8;
        ushortx8 kv[4], vv[4];
        for (int t = 0; t < 4; t++) {
            size_t g = (rowb + r4 + t) * 3072;
            kv[t] = *(const ushortx8*)(qkv + g + kcol + seg);
            vv[t] = *(const ushortx8*)(qkv + g + vcol + seg);
        }
        for (int e = 0; e < 8; e++) {
            ushortx4 ka, va;
            for (int t = 0; t < 4; t++) { ka[t] = kv[t][e]; va[t] = vv[t][e]; }
            *(ushortx4*)(Kt + (seg + e) * 132 + r4) = ka;
            *(ushortx4*)(Vt + (seg + e) * 132 + r4) = va;
        }
    }
    if (tid < 128) Vt[64 * 132 + tid] = 0x3f80;  // ones row (bf16 1.0)
    __syncthreads();

    floatx4 acc[5];
    for (int ni = 0; ni < 5; ni++) acc[ni] = floatx4{0.f, 0.f, 0.f, 0.f};
    int lm = lane & 15, lk = (lane >> 4) * 8;
    for (int k0 = 0; k0 < 128; k0 += 32) {
        short8 af = *(const short8*)(Kt + (w * 16 + lm) * 132 + k0 + lk);
        for (int ni = 0; ni < 5; ni++) {
            short8 bf = *(const short8*)(Vt + (ni * 16 + lm) * 132 + k0 + lk);
            acc[ni] = __builtin_amdgcn_mfma_f32_16x16x32_bf16(af, bf, acc[ni], 0, 0, 0);
        }
    }
    size_t base = ((size_t)(bb * H_ + h) * NC_ + c) * (size_t)(D_ * D_);
    int r0 = w * 16 + (lane >> 4) * 4;
    for (int ni = 0; ni < 4; ni++)
        for (int reg = 0; reg < 4; reg++)
            Sc[base + (size_t)(r0 + reg) * D_ + ni * 16 + lm] = acc[ni][reg];
    if (lm == 0) {
        size_t zb = ((size_t)(bb * H_ + h) * NC_ + c) * D_;
        for (int reg = 0; reg < 4; reg++) zc[zb + r0 + reg] = acc[4][reg];
    }
}

// ---------------- per-chunk attention (MFMA) — exact R11 scheme ----------------
__global__ __launch_bounds__(256) void attn_kernel(const unsigned short* __restrict__ qkv,
                                                   const float* __restrict__ Sc,
                                                   const float* __restrict__ zc,
                                                   unsigned short* __restrict__ attn) {
    int c = blockIdx.x, h = blockIdx.y, bb = blockIdx.z;
    __shared__ __align__(16) unsigned short qs[128 * 68];   // Q row-major, stride 68
    __shared__ __align__(16) unsigned short ks[128 * 68];   // K row-major
    __shared__ __align__(16) unsigned short vt[64 * 132];   // V^T
    __shared__ __align__(16) unsigned short ovl[128 * 36];  // S_prev^T (stride 68) then P panel (stride 36)
    __shared__ float zsh[64];
    int tid = threadIdx.x;
    int lane = tid & 63, w = tid >> 6;
    int lm = lane & 15, lq = lane >> 4;
    size_t rowb = (size_t)bb * T_ + (size_t)c * C_;
    int qcol = h * D_, kcol = E_ + h * D_, vcol = 2 * E_ + h * D_;

    // ---- stage q, k row-major (vector writes) ----
    for (int s = 0; s < 4; s++) {
        int off = s * 256 + tid;
        int r = off >> 3, seg = (off & 7) * 8;
        size_t g = (rowb + r) * 3072;
        ushortx8 q8 = *(const ushortx8*)(qkv + g + qcol + seg);
        ushortx8 k8 = *(const ushortx8*)(qkv + g + kcol + seg);
        *(ushortx8*)(qs + r * 68 + seg) = q8;
        *(ushortx8*)(ks + r * 68 + seg) = k8;
    }
    // ---- stage v transposed: 4 rows/thread, b64 column writes ----
    {
        int r4 = (tid >> 3) * 4;
        int seg = (tid & 7) * 8;
        ushortx8 vv[4];
        for (int t = 0; t < 4; t++)
            vv[t] = *(const ushortx8*)(qkv + (rowb + r4 + t) * 3072 + vcol + seg);
        for (int e = 0; e < 8; e++) {
            ushortx4 va;
            for (int t = 0; t < 4; t++) va[t] = vv[t][e];
            *(ushortx4*)(vt + (seg + e) * 132 + r4) = va;
        }
    }
    // ---- S_prev = sum_{j<c} Sc[j]  (store transposed bf16 into ovl, stride 68) ----
    {
        size_t scb = ((size_t)(bb * H_ + h) * NC_) * (size_t)(D_ * D_);
        int p = tid * 16;
        float a[16];
        for (int i = 0; i < 16; i++) a[i] = 0.f;
        for (int j = 0; j < c; j++) {
            const float* Sj = Sc + scb + (size_t)j * (D_ * D_) + p;
            for (int q = 0; q < 16; q += 4) {
                float4 f = *(const float4*)(Sj + q);
                a[q] += f.x; a[q + 1] += f.y; a[q + 2] += f.z; a[q + 3] += f.w;
            }
        }
        for (int i = 0; i < 16; i++) {
            int d = (p + i) >> 6, e = (p + i) & 63;
            ovl[e * 68 + d] = f2b(a[i]);
        }
    }
    // ---- z_prev (fp32) ----
    if (tid < 64) {
        size_t zb = ((size_t)(bb * H_ + h) * NC_) * D_;
        float zr = 0.f;
        for (int j = 0; j < c; j++) zr += zc[zb + (size_t)j * D_ + tid];
        zsh[tid] = zr;
    }
    __syncthreads();

    // ---- phase A: acc = Q @ S_prev ----
    floatx4 acc[2][4];
    for (int mi = 0; mi < 2; mi++) for (int ni = 0; ni < 4; ni++) acc[mi][ni] = floatx4{0.f, 0.f, 0.f, 0.f};
    for (int k0 = 0; k0 < 64; k0 += 32) {
        short8 aq[2];
        for (int mi = 0; mi < 2; mi++)
            aq[mi] = *(const short8*)(qs + (w * 32 + mi * 16 + lm) * 68 + k0 + lq * 8);
        for (int ni = 0; ni < 4; ni++) {
            short8 bs = *(const short8*)(ovl + (ni * 16 + lm) * 68 + k0 + lq * 8);
            for (int mi = 0; mi < 2; mi++)
                acc[mi][ni] = __builtin_amdgcn_mfma_f32_16x16x32_bf16(aq[mi], bs, acc[mi][ni], 0, 0, 0);
        }
    }
    // ---- dsum init: q . z_prev ----
    float dsum[2][4];
    {
        int d0 = lm * 4;
        float4 z4 = *(const float4*)(zsh + d0);
        for (int mi = 0; mi < 2; mi++)
            for (int reg = 0; reg < 4; reg++) {
                int row = w * 32 + mi * 16 + lq * 4 + reg;
                ushortx4 q4 = *(const ushortx4*)(qs + row * 68 + d0);
                dsum[mi][reg] = b2f(q4[0]) * z4.x + b2f(q4[1]) * z4.y + b2f(q4[2]) * z4.z + b2f(q4[3]) * z4.w;
            }
    }
    __syncthreads();  // all waves done reading S_prev^T from ovl before P writes

    // ---- intra-chunk j-loop: wave w only runs jt <= w (causality) ----
    for (int jt = 0; jt <= w; jt++) {
        floatx4 pa[2][2];
        for (int mi = 0; mi < 2; mi++) for (int ct = 0; ct < 2; ct++) pa[mi][ct] = floatx4{0.f, 0.f, 0.f, 0.f};
        for (int k0 = 0; k0 < 64; k0 += 32) {
            short8 aq[2];
            for (int mi = 0; mi < 2; mi++)
                aq[mi] = *(const short8*)(qs + (w * 32 + mi * 16 + lm) * 68 + k0 + lq * 8);
            for (int ct = 0; ct < 2; ct++) {
                short8 bk = *(const short8*)(ks + (jt * 32 + ct * 16 + lm) * 68 + k0 + lq * 8);
                for (int mi = 0; mi < 2; mi++)
                    pa[mi][ct] = __builtin_amdgcn_mfma_f32_16x16x32_bf16(aq[mi], bk, pa[mi][ct], 0, 0, 0);
            }
        }
        bool diag = (jt == w);
        for (int mi = 0; mi < 2; mi++)
            for (int ct = 0; ct < 2; ct++)
                for (int reg = 0; reg < 4; reg++) {
                    int il = mi * 16 + lq * 4 + reg;
                    int jl = ct * 16 + lm;
                    float v = pa[mi][ct][reg];
                    if (diag && jl > il) v = 0.f;
                    dsum[mi][reg] += v;
                    ovl[(w * 32 + il) * 36 + jl] = f2b(v);
                }
        short8 ap[2];
        for (int mi = 0; mi < 2; mi++)
            ap[mi] = *(const short8*)(ovl + (w * 32 + mi * 16 + lm) * 36 + lq * 8);
        for (int ni = 0; ni < 4; ni++) {
            short8 bv = *(const short8*)(vt + (ni * 16 + lm) * 132 + jt * 32 + lq * 8);
            for (int mi = 0; mi < 2; mi++)
                acc[mi][ni] = __builtin_amdgcn_mfma_f32_16x16x32_bf16(ap[mi], bv, acc[mi][ni], 0, 0, 0);
        }
    }

    // ---- reduce dsum across the 16-lane col group ----
    for (int off = 1; off < 16; off <<= 1)
        for (int mi = 0; mi < 2; mi++)
            for (int reg = 0; reg < 4; reg++)
                dsum[mi][reg] += __shfl_xor(dsum[mi][reg], off);

    // ---- epilogue: out = num / den ----
    for (int mi = 0; mi < 2; mi++)
        for (int reg = 0; reg < 4; reg++) {
            float inv = 1.f / (dsum[mi][reg] + EPS_);
            int row = w * 32 + mi * 16 + lq * 4 + reg;
            for (int ni = 0; ni < 4; ni++)
                attn[(rowb + row) * E_ + h * D_ + ni * 16 + lm] = f2b(acc[mi][ni][reg] * inv);
        }
}

extern "C" void kernel_launch(void* const* d_in, const int* in_sizes, int n_in,
                              void* d_out, int out_size, void* d_ws, size_t ws_size,
                              hipStream_t stream) {
    const float* x  = (const float*)d_in[0];
    const float* Wq = (const float*)d_in[1];
    const float* Wk = (const float*)d_in[2];
    const float* Wv = (const float*)d_in[3];
    const float* Wo = (const float*)d_in[4];
    const float* bo = (const float*)d_in[5];
    float* out = (float*)d_out;

    const size_t MB = 1024 * 1024;
    uint8_t* ws = (uint8_t*)d_ws;
    unsigned short* xb    = (unsigned short*)(ws + 0);        // 8 MB, reused as attn buffer
    unsigned short* wb    = (unsigned short*)(ws + 8 * MB);   // 8 MB (Wq|Wk|Wv|Wo bf16)
    unsigned short* wob   = wb + 3 * E_ * E_;
    unsigned short* qkvb  = (unsigned short*)(ws + 16 * MB);  // 24 MB
    float* Sc = (float*)(ws + 40 * MB);                       // 8 MB
    float* zc = (float*)(ws + 48 * MB);                       // 128 KB
    unsigned short* attnb = xb;

    convert_all<<<(M_ * E_ + 4 * E_ * E_) / 1024, 256, 0, stream>>>(x, Wq, Wk, Wv, Wo, xb);

    gemm_qkv<<<dim3(48, 64), 256, 0, stream>>>(xb, wb, qkvb);
    chunk_sums<<<dim3(NC_, H_, B_), 256, 0, stream>>>(qkvb, Sc, zc);
    attn_kernel<<<dim3(NC_, H_, B_), 256, 0, stream>>>(qkvb, Sc, zc, attnb);
    gemm_out<<<dim3(16, 64), 256, 0, stream>>>(attnb, wob, bo, out);
}

// Round 14
// 164.399 us; speedup vs baseline: 1.0453x; 1.0453x over previous
//
#include <hip/hip_runtime.h>
#include <hip/hip_bf16.h>
#include <stdint.h>

typedef __attribute__((ext_vector_type(4)))  float  floatx4;
typedef __attribute__((ext_vector_type(8)))  short  short8;
typedef __attribute__((ext_vector_type(8)))  unsigned short ushortx8;
typedef __attribute__((ext_vector_type(4)))  unsigned short ushortx4;

#define B_  2
#define T_  2048
#define E_  1024
#define H_  16
#define D_  64
#define C_  128
#define NC_ 16
#define M_  4096   /* B*T */
#define EPS_ 1e-5f

__device__ __forceinline__ unsigned short f2b(float f) {
    union { float f; unsigned int u; } v; v.f = f;
    unsigned int r = v.u + 0x7fffu + ((v.u >> 16) & 1u);
    return (unsigned short)(r >> 16);
}
__device__ __forceinline__ float b2f(unsigned short b) {
    union { unsigned int u; float f; } v; v.u = ((unsigned int)b) << 16;
    return v.f;
}

// Swizzled fragment staging (R3/R4; R7/R9/R10/R13 errata):
//   staging tile = 16 rows x 32 k (1 KB). lane i fetches global (row = i>>2,
//   kseg = (i&3) ^ ((i>>3)&3)) -> LDS slot i (16B). Fragment read: lane l
//   reads slot sigma(l&15, l>>4) with a WAVE-UNIFORM tile base (R7 errata).
//   R9: fragment operands MUST come from LDS. R10: don't re-swizzle blockIdx.
//   R13: 64x128@6/CU beats 64x64@8/CU — occupancy gradient exhausted.
__device__ __forceinline__ int stage_seg(int i) { return (i & 3) ^ ((i >> 3) & 3); }
__device__ __forceinline__ int frag_slot(int lane) {
    int m = lane & 15, q = lane >> 4;
    return m * 4 + (q ^ ((m >> 1) & 3));
}

// ---------------- fused fp32 -> bf16 convert: x | Wq | Wk | Wv | Wo ----------------
__global__ __launch_bounds__(256) void convert_all(const float* __restrict__ x,
                                                   const float* __restrict__ Wq,
                                                   const float* __restrict__ Wk,
                                                   const float* __restrict__ Wv,
                                                   const float* __restrict__ Wo,
                                                   unsigned short* __restrict__ dst) {
    int i = (blockIdx.x * 256 + threadIdx.x) * 4;
    const float* s; int off;
    if (i < M_ * E_) { s = x; off = i; }
    else {
        int j = i - M_ * E_;
        int which = j >> 20;
        s = (which == 0) ? Wq : (which == 1) ? Wk : (which == 2) ? Wv : Wo;
        off = j & ((1 << 20) - 1);
    }
    float4 f = *(const float4*)(s + off);
    ushortx4 o;
    o[0] = f2b(f.x); o[1] = f2b(f.y); o[2] = f2b(f.z); o[3] = f2b(f.w);
    *(ushortx4*)(dst + i) = o;
}

// ---------------- QKV projection GEMM: C[4096,3072] = X @ W^T, phi on q,k ----------------
// R6 config (best: 43us) + R14 vectorized epilogue: C-tile bounced through
// the (free after K-loop) staging LDS at row-stride 68 (4-row bank shift =
// 8 banks -> conflict-free writes), read back as 8-elem row segments ->
// 4 x 16B coalesced stores/thread instead of 32 x 2B scattered stores.
__global__ __launch_bounds__(256) void gemm_qkv(const unsigned short* __restrict__ A,
                                                const unsigned short* __restrict__ Bm,
                                                unsigned short* __restrict__ Cb) {
    const int N = 3 * E_, K = E_;
    __shared__ __align__(16) unsigned short smem[12288];   // 24 KB: at = smem[0:4096), bt = smem[4096:12288)
    unsigned short* at = smem;
    unsigned short* bt = smem + 4096;
    int tid = threadIdx.x;
    int wave = tid >> 6, lane = tid & 63;
    int wr = wave >> 1, wc = wave & 1;
    int m = lane & 15, q = lane >> 4;
    int srow = lane >> 2, sseg = stage_seg(lane);
    int fs = frag_slot(lane);
    int row0 = blockIdx.y * 64, col0 = blockIdx.x * 128;
    floatx4 acc[2][4];
    for (int i = 0; i < 2; i++) for (int j = 0; j < 4; j++) acc[i][j] = floatx4{0.f, 0.f, 0.f, 0.f};

    for (int k0 = 0; k0 < K; k0 += 64) {
        __syncthreads();
        for (int p = 0; p < 2; p++) {               // A: 8 tiles, 2 per wave
            int t = p * 4 + wave;
            const unsigned short* ga = A + (size_t)(row0 + (t & 3) * 16 + srow) * K + k0 + (t >> 2) * 32 + sseg * 8;
            __builtin_amdgcn_global_load_lds((const __attribute__((address_space(1))) unsigned int*)ga,
                (__attribute__((address_space(3))) unsigned int*)(at + t * 512), 16, 0, 0);
        }
        for (int p = 0; p < 4; p++) {               // B: 16 tiles, 4 per wave
            int u = p * 4 + wave;
            const unsigned short* gb = Bm + (size_t)(col0 + (u & 7) * 16 + srow) * K + k0 + (u >> 3) * 32 + sseg * 8;
            __builtin_amdgcn_global_load_lds((const __attribute__((address_space(1))) unsigned int*)gb,
                (__attribute__((address_space(3))) unsigned int*)(bt + u * 512), 16, 0, 0);
        }
        __syncthreads();
        for (int kh = 0; kh < 2; kh++) {
            short8 af[2], bf[4];
            for (int mi = 0; mi < 2; mi++) af[mi] = *(const short8*)(at + (kh * 4 + wr * 2 + mi) * 512 + fs * 8);
            for (int ni = 0; ni < 4; ni++) bf[ni] = *(const short8*)(bt + (kh * 8 + wc * 4 + ni) * 512 + fs * 8);
            for (int mi = 0; mi < 2; mi++)
                for (int ni = 0; ni < 4; ni++)
                    acc[mi][ni] = __builtin_amdgcn_mfma_f32_16x16x32_bf16(af[mi], bf[ni], acc[mi][ni], 0, 0, 0);
        }
    }

    // ---- R14 epilogue: LDS bounce -> coalesced 16B stores ----
    __syncthreads();                                // all waves done with staging LDS
    unsigned short* epi = smem + wave * 2176;       // 32 rows x stride 68 per wave
    bool isphi = (col0 < 2 * E_);                   // block-uniform (2048 % 128 == 0)
    for (int mi = 0; mi < 2; mi++)
        for (int ni = 0; ni < 4; ni++)
            for (int reg = 0; reg < 4; reg++) {
                int lr = mi * 16 + q * 4 + reg;     // local row within wave tile
                float v = acc[mi][ni][reg];
                if (isphi) v = (v > 0.f) ? (v + 1.f) : __expf(v);
                epi[lr * 68 + ni * 16 + m] = f2b(v);
            }
    // wave-local write->read (compiler inserts lgkmcnt wait); no cross-wave sharing
    for (int i = 0; i < 4; i++) {
        int s = i * 64 + lane;                      // 256 slots = 32 rows x 8 segs
        int lr = s >> 3, seg = s & 7;
        const unsigned short* p = epi + lr * 68 + seg * 8;
        ushortx4 lo = *(const ushortx4*)(p);
        ushortx4 hi = *(const ushortx4*)(p + 4);
        ushortx8 val;
        for (int e = 0; e < 4; e++) { val[e] = lo[e]; val[e + 4] = hi[e]; }
        int row = row0 + wr * 32 + lr;
        int col = col0 + wc * 64 + seg * 8;
        *(ushortx8*)(Cb + (size_t)row * N + col) = val;
    }
}

// ---------------- Output GEMM: out[4096,1024] = attn @ Wo^T + bo (fp32 out) ----------------
// Exact R6 config: 64x64 tile, BK=64, grid 16x64 = 1024 = 4/CU, LDS 16 KB.
__global__ __launch_bounds__(256) void gemm_out(const unsigned short* __restrict__ A,
                                                const unsigned short* __restrict__ Bm,
                                                const float* __restrict__ bias,
                                                float* __restrict__ Cf) {
    const int N = E_, K = E_;
    __shared__ __align__(16) unsigned short at[8 * 512];
    __shared__ __align__(16) unsigned short bt[8 * 512];
    int tid = threadIdx.x;
    int wave = tid >> 6, lane = tid & 63;
    int wr = wave >> 1, wc = wave & 1;
    int m = lane & 15, q = lane >> 4;
    int srow = lane >> 2, sseg = stage_seg(lane);
    int fs = frag_slot(lane);
    int row0 = blockIdx.y * 64, col0 = blockIdx.x * 64;
    floatx4 acc[2][2];
    for (int i = 0; i < 2; i++) for (int j = 0; j < 2; j++) acc[i][j] = floatx4{0.f, 0.f, 0.f, 0.f};

    for (int k0 = 0; k0 < K; k0 += 64) {
        __syncthreads();
        for (int p = 0; p < 2; p++) {
            int t = p * 4 + wave;
            int rt = t & 3, kh = t >> 2;
            const unsigned short* ga = A  + (size_t)(row0 + rt * 16 + srow) * K + k0 + kh * 32 + sseg * 8;
            const unsigned short* gb = Bm + (size_t)(col0 + rt * 16 + srow) * K + k0 + kh * 32 + sseg * 8;
            __builtin_amdgcn_global_load_lds((const __attribute__((address_space(1))) unsigned int*)ga,
                (__attribute__((address_space(3))) unsigned int*)(at + t * 512), 16, 0, 0);
            __builtin_amdgcn_global_load_lds((const __attribute__((address_space(1))) unsigned int*)gb,
                (__attribute__((address_space(3))) unsigned int*)(bt + t * 512), 16, 0, 0);
        }
        __syncthreads();
        for (int kh = 0; kh < 2; kh++) {
            short8 af[2], bf[2];
            for (int mi = 0; mi < 2; mi++) af[mi] = *(const short8*)(at + (kh * 4 + wr * 2 + mi) * 512 + fs * 8);
            for (int ci = 0; ci < 2; ci++) bf[ci] = *(const short8*)(bt + (kh * 4 + wc * 2 + ci) * 512 + fs * 8);
            for (int mi = 0; mi < 2; mi++)
                for (int ci = 0; ci < 2; ci++)
                    acc[mi][ci] = __builtin_amdgcn_mfma_f32_16x16x32_bf16(af[mi], bf[ci], acc[mi][ci], 0, 0, 0);
        }
    }
    int qrow = q * 4;
    for (int ci = 0; ci < 2; ci++) {
        int col = col0 + wc * 32 + ci * 16 + m;
        float bv = bias[col];
        for (int mi = 0; mi < 2; mi++)
            for (int r2 = 0; r2 < 4; r2++) {
                int row = row0 + wr * 32 + mi * 16 + qrow + r2;
                Cf[(size_t)row * N + col] = acc[mi][ci][r2] + bv;
            }
    }
}

// ---------------- per-chunk S_c = k_c^T v_c (64x64) and z_c (MFMA) ----------------
__global__ __launch_bounds__(256) void chunk_sums(const unsigned short* __restrict__ qkv,
                                                  float* __restrict__ Sc, float* __restrict__ zc) {
    int c = blockIdx.x, h = blockIdx.y, bb = blockIdx.z;
    __shared__ __align__(16) unsigned short Kt[64 * 132];   // K^T: [d][t], stride 132
    __shared__ __align__(16) unsigned short Vt[80 * 132];   // V^T rows 0..63; row 64 = ones
    int tid = threadIdx.x;
    int lane = tid & 63, w = tid >> 6;
    size_t rowb = (size_t)bb * T_ + (size_t)c * C_;
    int kcol = E_ + h * D_, vcol = 2 * E_ + h * D_;

    {
        int r4 = (tid >> 3) * 4;            // covers 128 rows
        int seg = (tid & 7) * 8;
        ushortx8 kv[4], vv[4];
        for (int t = 0; t < 4; t++) {
            size_t g = (rowb + r4 + t) * 3072;
            kv[t] = *(const ushortx8*)(qkv + g + kcol + seg);
            vv[t] = *(const ushortx8*)(qkv + g + vcol + seg);
        }
        for (int e = 0; e < 8; e++) {
            ushortx4 ka, va;
            for (int t = 0; t < 4; t++) { ka[t] = kv[t][e]; va[t] = vv[t][e]; }
            *(ushortx4*)(Kt + (seg + e) * 132 + r4) = ka;
            *(ushortx4*)(Vt + (seg + e) * 132 + r4) = va;
        }
    }
    if (tid < 128) Vt[64 * 132 + tid] = 0x3f80;  // ones row (bf16 1.0)
    __syncthreads();

    floatx4 acc[5];
    for (int ni = 0; ni < 5; ni++) acc[ni] = floatx4{0.f, 0.f, 0.f, 0.f};
    int lm = lane & 15, lk = (lane >> 4) * 8;
    for (int k0 = 0; k0 < 128; k0 += 32) {
        short8 af = *(const short8*)(Kt + (w * 16 + lm) * 132 + k0 + lk);
        for (int ni = 0; ni < 5; ni++) {
            short8 bf = *(const short8*)(Vt + (ni * 16 + lm) * 132 + k0 + lk);
            acc[ni] = __builtin_amdgcn_mfma_f32_16x16x32_bf16(af, bf, acc[ni], 0, 0, 0);
        }
    }
    size_t base = ((size_t)(bb * H_ + h) * NC_ + c) * (size_t)(D_ * D_);
    int r0 = w * 16 + (lane >> 4) * 4;
    for (int ni = 0; ni < 4; ni++)
        for (int reg = 0; reg < 4; reg++)
            Sc[base + (size_t)(r0 + reg) * D_ + ni * 16 + lm] = acc[ni][reg];
    if (lm == 0) {
        size_t zb = ((size_t)(bb * H_ + h) * NC_ + c) * D_;
        for (int reg = 0; reg < 4; reg++) zc[zb + r0 + reg] = acc[4][reg];
    }
}

// ---------------- per-chunk attention (MFMA) — exact R11 scheme ----------------
__global__ __launch_bounds__(256) void attn_kernel(const unsigned short* __restrict__ qkv,
                                                   const float* __restrict__ Sc,
                                                   const float* __restrict__ zc,
                                                   unsigned short* __restrict__ attn) {
    int c = blockIdx.x, h = blockIdx.y, bb = blockIdx.z;
    __shared__ __align__(16) unsigned short qs[128 * 68];   // Q row-major, stride 68
    __shared__ __align__(16) unsigned short ks[128 * 68];   // K row-major
    __shared__ __align__(16) unsigned short vt[64 * 132];   // V^T
    __shared__ __align__(16) unsigned short ovl[128 * 36];  // S_prev^T (stride 68) then P panel (stride 36)
    __shared__ float zsh[64];
    int tid = threadIdx.x;
    int lane = tid & 63, w = tid >> 6;
    int lm = lane & 15, lq = lane >> 4;
    size_t rowb = (size_t)bb * T_ + (size_t)c * C_;
    int qcol = h * D_, kcol = E_ + h * D_, vcol = 2 * E_ + h * D_;

    // ---- stage q, k row-major (vector writes) ----
    for (int s = 0; s < 4; s++) {
        int off = s * 256 + tid;
        int r = off >> 3, seg = (off & 7) * 8;
        size_t g = (rowb + r) * 3072;
        ushortx8 q8 = *(const ushortx8*)(qkv + g + qcol + seg);
        ushortx8 k8 = *(const ushortx8*)(qkv + g + kcol + seg);
        *(ushortx8*)(qs + r * 68 + seg) = q8;
        *(ushortx8*)(ks + r * 68 + seg) = k8;
    }
    // ---- stage v transposed: 4 rows/thread, b64 column writes ----
    {
        int r4 = (tid >> 3) * 4;
        int seg = (tid & 7) * 8;
        ushortx8 vv[4];
        for (int t = 0; t < 4; t++)
            vv[t] = *(const ushortx8*)(qkv + (rowb + r4 + t) * 3072 + vcol + seg);
        for (int e = 0; e < 8; e++) {
            ushortx4 va;
            for (int t = 0; t < 4; t++) va[t] = vv[t][e];
            *(ushortx4*)(vt + (seg + e) * 132 + r4) = va;
        }
    }
    // ---- S_prev = sum_{j<c} Sc[j]  (store transposed bf16 into ovl, stride 68) ----
    {
        size_t scb = ((size_t)(bb * H_ + h) * NC_) * (size_t)(D_ * D_);
        int p = tid * 16;
        float a[16];
        for (int i = 0; i < 16; i++) a[i] = 0.f;
        for (int j = 0; j < c; j++) {
            const float* Sj = Sc + scb + (size_t)j * (D_ * D_) + p;
            for (int q = 0; q < 16; q += 4) {
                float4 f = *(const float4*)(Sj + q);
                a[q] += f.x; a[q + 1] += f.y; a[q + 2] += f.z; a[q + 3] += f.w;
            }
        }
        for (int i = 0; i < 16; i++) {
            int d = (p + i) >> 6, e = (p + i) & 63;
            ovl[e * 68 + d] = f2b(a[i]);
        }
    }
    // ---- z_prev (fp32) ----
    if (tid < 64) {
        size_t zb = ((size_t)(bb * H_ + h) * NC_) * D_;
        float zr = 0.f;
        for (int j = 0; j < c; j++) zr += zc[zb + (size_t)j * D_ + tid];
        zsh[tid] = zr;
    }
    __syncthreads();

    // ---- phase A: acc = Q @ S_prev ----
    floatx4 acc[2][4];
    for (int mi = 0; mi < 2; mi++) for (int ni = 0; ni < 4; ni++) acc[mi][ni] = floatx4{0.f, 0.f, 0.f, 0.f};
    for (int k0 = 0; k0 < 64; k0 += 32) {
        short8 aq[2];
        for (int mi = 0; mi < 2; mi++)
            aq[mi] = *(const short8*)(qs + (w * 32 + mi * 16 + lm) * 68 + k0 + lq * 8);
        for (int ni = 0; ni < 4; ni++) {
            short8 bs = *(const short8*)(ovl + (ni * 16 + lm) * 68 + k0 + lq * 8);
            for (int mi = 0; mi < 2; mi++)
                acc[mi][ni] = __builtin_amdgcn_mfma_f32_16x16x32_bf16(aq[mi], bs, acc[mi][ni], 0, 0, 0);
        }
    }
    // ---- dsum init: q . z_prev ----
    float dsum[2][4];
    {
        int d0 = lm * 4;
        float4 z4 = *(const float4*)(zsh + d0);
        for (int mi = 0; mi < 2; mi++)
            for (int reg = 0; reg < 4; reg++) {
                int row = w * 32 + mi * 16 + lq * 4 + reg;
                ushortx4 q4 = *(const ushortx4*)(qs + row * 68 + d0);
                dsum[mi][reg] = b2f(q4[0]) * z4.x + b2f(q4[1]) * z4.y + b2f(q4[2]) * z4.z + b2f(q4[3]) * z4.w;
            }
    }
    __syncthreads();  // all waves done reading S_prev^T from ovl before P writes

    // ---- intra-chunk j-loop: wave w only runs jt <= w (causality) ----
    for (int jt = 0; jt <= w; jt++) {
        floatx4 pa[2][2];
        for (int mi = 0; mi < 2; mi++) for (int ct = 0; ct < 2; ct++) pa[mi][ct] = floatx4{0.f, 0.f, 0.f, 0.f};
        for (int k0 = 0; k0 < 64; k0 += 32) {
            short8 aq[2];
            for (int mi = 0; mi < 2; mi++)
                aq[mi] = *(const short8*)(qs + (w * 32 + mi * 16 + lm) * 68 + k0 + lq * 8);
            for (int ct = 0; ct < 2; ct++) {
                short8 bk = *(const short8*)(ks + (jt * 32 + ct * 16 + lm) * 68 + k0 + lq * 8);
                for (int mi = 0; mi < 2; mi++)
                    pa[mi][ct] = __builtin_amdgcn_mfma_f32_16x16x32_bf16(aq[mi], bk, pa[mi][ct], 0, 0, 0);
            }
        }
        bool diag = (jt == w);
        for (int mi = 0; mi < 2; mi++)
            for (int ct = 0; ct < 2; ct++)
                for (int reg = 0; reg < 4; reg++) {
                    int il = mi * 16 + lq * 4 + reg;
                    int jl = ct * 16 + lm;
                    float v = pa[mi][ct][reg];
                    if (diag && jl > il) v = 0.f;
                    dsum[mi][reg] += v;
                    ovl[(w * 32 + il) * 36 + jl] = f2b(v);
                }
        short8 ap[2];
        for (int mi = 0; mi < 2; mi++)
            ap[mi] = *(const short8*)(ovl + (w * 32 + mi * 16 + lm) * 36 + lq * 8);
        for (int ni = 0; ni < 4; ni++) {
            short8 bv = *(const short8*)(vt + (ni * 16 + lm) * 132 + jt * 32 + lq * 8);
            for (int mi = 0; mi < 2; mi++)
                acc[mi][ni] = __builtin_amdgcn_mfma_f32_16x16x32_bf16(ap[mi], bv, acc[mi][ni], 0, 0, 0);
        }
    }

    // ---- reduce dsum across the 16-lane col group ----
    for (int off = 1; off < 16; off <<= 1)
        for (int mi = 0; mi < 2; mi++)
            for (int reg = 0; reg < 4; reg++)
                dsum[mi][reg] += __shfl_xor(dsum[mi][reg], off);

    // ---- epilogue: out = num / den ----
    for (int mi = 0; mi < 2; mi++)
        for (int reg = 0; reg < 4; reg++) {
            float inv = 1.f / (dsum[mi][reg] + EPS_);
            int row = w * 32 + mi * 16 + lq * 4 + reg;
            for (int ni = 0; ni < 4; ni++)
                attn[(rowb + row) * E_ + h * D_ + ni * 16 + lm] = f2b(acc[mi][ni][reg] * inv);
        }
}

extern "C" void kernel_launch(void* const* d_in, const int* in_sizes, int n_in,
                              void* d_out, int out_size, void* d_ws, size_t ws_size,
                              hipStream_t stream) {
    const float* x  = (const float*)d_in[0];
    const float* Wq = (const float*)d_in[1];
    const float* Wk = (const float*)d_in[2];
    const float* Wv = (const float*)d_in[3];
    const float* Wo = (const float*)d_in[4];
    const float* bo = (const float*)d_in[5];
    float* out = (float*)d_out;

    const size_t MB = 1024 * 1024;
    uint8_t* ws = (uint8_t*)d_ws;
    unsigned short* xb    = (unsigned short*)(ws + 0);        // 8 MB, reused as attn buffer
    unsigned short* wb    = (unsigned short*)(ws + 8 * MB);   // 8 MB (Wq|Wk|Wv|Wo bf16)
    unsigned short* wob   = wb + 3 * E_ * E_;
    unsigned short* qkvb  = (unsigned short*)(ws + 16 * MB);  // 24 MB
    float* Sc = (float*)(ws + 40 * MB);                       // 8 MB
    float* zc = (float*)(ws + 48 * MB);                       // 128 KB
    unsigned short* attnb = xb;

    convert_all<<<(M_ * E_ + 4 * E_ * E_) / 1024, 256, 0, stream>>>(x, Wq, Wk, Wv, Wo, xb);

    gemm_qkv<<<dim3(24, 64), 256, 0, stream>>>(xb, wb, qkvb);
    chunk_sums<<<dim3(NC_, H_, B_), 256, 0, stream>>>(qkvb, Sc, zc);
    attn_kernel<<<dim3(NC_, H_, B_), 256, 0, stream>>>(qkvb, Sc, zc, attnb);
    gemm_out<<<dim3(16, 64), 256, 0, stream>>>(attnb, wob, bo, out);
}